// Round 11
// baseline (356.710 us; speedup 1.0000x reference)
//
#include <hip/hip_runtime.h>

typedef unsigned short u16;
typedef unsigned int   u32;
typedef __attribute__((ext_vector_type(4))) float  f32x4;
typedef __attribute__((ext_vector_type(8))) __bf16 bf16x8;

#define EMBED 2048
#define NH    16
#define NKV   4
#define HD    128
#define TT    2048
#define BB    2
#define MROWS (BB*TT)
#define QSCALE 0.08838834764831845f

#define QELEMS ((size_t)BB*NH*TT*HD)
#define KELEMS ((size_t)BB*NKV*TT*HD)

#define AS1(p) (__attribute__((address_space(1))) void*)(void*)(p)
#define AS3(p) (__attribute__((address_space(3))) void*)(void*)(p)

// NOTE (r7): 256^2 8-phase GEMM at 192 blocks was -10us (75% CU coverage) — keep 128^2.
// NOTE (r9): single-buffer attn (3 blk/CU) was -24us — TLP is not the attn lever.
// NOTE (r10): in-reg softmax = null on time but correct; VALU 38->50, conflicts -11%.
//             Limiter = per-step intensity: 32 ds_reads buy only 32 MFMA at 16 q-rows/wave.
// r11: 32 q-rows/wave — every K/V fragment read feeds 2 MFMAs; blocks halve to 128-row tiles.

static __device__ __forceinline__ u16 f2b(float f){
  union { float f; u32 u; } v; v.f = f;
  u32 u = v.u;
  u32 r = u + 0x7FFFu + ((u >> 16) & 1u);   // RNE
  return (u16)(r >> 16);
}

// ---------------- fp32 -> bf16 convert (x) ----------------
__global__ __launch_bounds__(256) void cvt_f32_bf16(const float* __restrict__ in,
                                                    u16* __restrict__ out, int n4){
  int i = blockIdx.x * 256 + threadIdx.x;
  if (i >= n4) return;
  float4 v = ((const float4*)in)[i];
  uint2 o;
  o.x = (u32)f2b(v.x) | ((u32)f2b(v.y) << 16);
  o.y = (u32)f2b(v.z) | ((u32)f2b(v.w) << 16);
  ((uint2*)out)[i] = o;
}

// ---------------- fp32 [R][C] -> bf16 [C][R], two matrices per launch (z-dim) ----------------
__global__ __launch_bounds__(256) void trans_w2(const float* __restrict__ in0, u16* __restrict__ out0,
                                                const float* __restrict__ in1, u16* __restrict__ out1,
                                                int R, int C){
  const float* in = blockIdx.z ? in1 : in0;
  u16*        out = blockIdx.z ? out1 : out0;
  __shared__ u16 tile[32][33];
  int c0 = blockIdx.x * 32, r0 = blockIdx.y * 32;
  int tx = threadIdx.x & 31, ty = threadIdx.x >> 5;   // 32 x 8
  #pragma unroll
  for (int j = 0; j < 32; j += 8)
    tile[ty + j][tx] = f2b(in[(size_t)(r0 + ty + j) * C + c0 + tx]);
  __syncthreads();
  #pragma unroll
  for (int j = 0; j < 32; j += 8)
    out[(size_t)(c0 + ty + j) * R + r0 + tx] = tile[tx][ty + j];
}

// ---------------- bf16 [BH][T][D] -> [BH][D][T]  (V for PV fragment reads) ----------------
__global__ __launch_bounds__(256) void trans_v(const u16* __restrict__ in,
                                               u16* __restrict__ out){
  __shared__ u16 tile[32][33];
  int d0 = (blockIdx.x & 3) * 32;            // D/32 = 4
  int t0 = ((blockIdx.x >> 2) & 63) * 32;    // T/32 = 64
  int bh = blockIdx.x >> 8;                  // B*NKV = 8
  const u16* ip = in  + (size_t)bh * TT * HD;
  u16*       op = out + (size_t)bh * TT * HD;
  int tx = threadIdx.x & 31, ty = threadIdx.x >> 5;
  #pragma unroll
  for (int j = 0; j < 32; j += 8)
    tile[ty + j][tx] = ip[(size_t)(t0 + ty + j) * HD + d0 + tx];
  __syncthreads();
  #pragma unroll
  for (int j = 0; j < 32; j += 8)
    op[(size_t)(d0 + ty + j) * TT + t0 + tx] = tile[tx][ty + j];
}

// ---------------- bf16 GEMM: C[M,N] = A[M,K] * Bt[N,K]^T (128^2, m97 structure) ----------------
template<int EPI>
__global__ __launch_bounds__(256)
void gemm_bt(const u16* __restrict__ A, const u16* __restrict__ Bt,
             void* __restrict__ outp, int N, int K){
  __shared__ __align__(16) u16 As[2][128*32];
  __shared__ __align__(16) u16 Bs[2][128*32];
  int tid  = threadIdx.x;
  int lane = tid & 63, w = tid >> 6;
  int nwg = gridDim.x;
  int bid = blockIdx.x;
  bid = (bid & 7) * (nwg >> 3) + (bid >> 3);      // XCD swizzle (nwg % 8 == 0 always here)
  int nbn  = N >> 7;
  int brow = (bid / nbn) * 128;
  int bcol = (bid % nbn) * 128;

  auto stage = [&](int buf, int kt){
    #pragma unroll
    for (int j = 0; j < 2; ++j){
      int boff  = w * 2048 + j * 1024;
      int chunk = (boff >> 4) + lane;
      int row   = chunk >> 2;
      int cko   = chunk & 3;
      const u16* ga = A  + (size_t)(brow + row) * K + kt + cko * 8;
      const u16* gb = Bt + (size_t)(bcol + row) * K + kt + cko * 8;
      __builtin_amdgcn_global_load_lds(AS1(ga), AS3(&As[buf][boff >> 1]), 16, 0, 0);
      __builtin_amdgcn_global_load_lds(AS1(gb), AS3(&Bs[buf][boff >> 1]), 16, 0, 0);
    }
  };

  int lr = lane & 15, lg = lane >> 4, lk = lg * 8;
  int wr = (w >> 1) * 64, wc = (w & 1) * 64;

  f32x4 acc[4][4];
  #pragma unroll
  for (int m = 0; m < 4; ++m)
    #pragma unroll
    for (int n = 0; n < 4; ++n)
      #pragma unroll
      for (int r = 0; r < 4; ++r) acc[m][n][r] = 0.f;

  int NT = K >> 5;
  stage(0, 0);
  asm volatile("s_waitcnt vmcnt(0)" ::: "memory");
  __syncthreads();
  int cur = 0;
  for (int t = 0; t < NT; ++t){
    if (t + 1 < NT) stage(cur ^ 1, (t + 1) * 32);
    const u16* as = As[cur];
    const u16* bs = Bs[cur];
    bf16x8 af[4], bfv[4];
    #pragma unroll
    for (int m = 0; m < 4; ++m) af[m]  = *(const bf16x8*)(as + (wr + m*16 + lr)*32 + lk);
    #pragma unroll
    for (int n = 0; n < 4; ++n) bfv[n] = *(const bf16x8*)(bs + (wc + n*16 + lr)*32 + lk);
    #pragma unroll
    for (int m = 0; m < 4; ++m)
      #pragma unroll
      for (int n = 0; n < 4; ++n)
        acc[m][n] = __builtin_amdgcn_mfma_f32_16x16x32_bf16(af[m], bfv[n], acc[m][n], 0, 0, 0);
    asm volatile("s_waitcnt vmcnt(0)" ::: "memory");
    __syncthreads();
    cur ^= 1;
  }

  if (EPI == 0){
    float* o = (float*)outp;
    #pragma unroll
    for (int m = 0; m < 4; ++m)
      #pragma unroll
      for (int r = 0; r < 4; ++r){
        int rowg = brow + wr + m*16 + lg*4 + r;
        float* orow = o + (size_t)rowg * N + bcol + wc + lr;
        #pragma unroll
        for (int n = 0; n < 4; ++n) orow[n*16] = acc[m][n][r];
      }
  } else {
    u16* qb = (u16*)outp;
    u16* kb = qb + QELEMS;
    u16* vb = kb + KELEMS;
    int hb = bcol >> 7;                 // 0..23
    int b  = brow >> 11;
    u16* hp; float s;
    if (hb < 16)      { hp = qb + ((size_t)(b*NH  +  hb     )) * TT * HD; s = QSCALE; }
    else if (hb < 20) { hp = kb + ((size_t)(b*NKV + (hb-16))) * TT * HD; s = 1.0f; }
    else              { hp = vb + ((size_t)(b*NKV + (hb-20))) * TT * HD; s = 1.0f; }
    #pragma unroll
    for (int m = 0; m < 4; ++m)
      #pragma unroll
      for (int r = 0; r < 4; ++r){
        int t = (brow + wr + m*16 + lg*4 + r) & (TT - 1);
        #pragma unroll
        for (int n = 0; n < 4; ++n){
          int d = wc + n*16 + lr;
          hp[(size_t)t * HD + d] = f2b(acc[m][n][r] * s);
        }
      }
  }
}

// ---------------- flash attention v5: swapped QK^T, in-reg softmax, 32 q-rows/wave ----------------
// 128-row q-tile per block (4 waves x 32 rows as two 16-row groups A/B sharing K/V fragments):
// 16 K-reads + 16 V-reads -> 64 MFMA per step (2x intensity of v4). Unpaired qt, descending
// dispatch order (long blocks first), 512 blocks, 2/CU. Permutation verified in r10 (absmax ok).
__global__ __launch_bounds__(256, 2)
void attn_kernel(const u16* __restrict__ qb, const u16* __restrict__ kb,
                 const u16* __restrict__ vtb, u16* __restrict__ ob){
  __shared__ __align__(16) u16 Ks[2][64*128];   // [kv 64][d 128], chunk-swizzled
  __shared__ __align__(16) u16 Vs[2][128*64];   // [d 128][kv 64], chunk-swizzled
  int tid = threadIdx.x, lane = tid & 63, w = tid >> 6;
  int bid = blockIdx.x;                         // 512 blocks
  int decoded = (bid & 7) * 64 + (bid >> 3);    // XCD chunking: grp == bid&7
  int grp = decoded >> 6;                       // (b, hkv) group -> one XCD's L2
  int i   = decoded & 63;
  int qt  = 15 - (i & 15);                      // descending qt in dispatch order
  int h   = (grp & 3) * 4 + (i >> 4);
  int b   = grp >> 2;
  int hkv = h >> 2;
  int j  = lane & 15, g = lane >> 4, lk = g * 8;
  int gh = g >> 1;
  int sw = (j & 7) << 3;                        // read-side XOR (elements)

  const u16* qbase = qb  + ((size_t)b * NH  + h  ) * TT * HD;
  const u16* kbase = kb  + ((size_t)b * NKV + hkv) * TT * HD;
  const u16* vbase = vtb + ((size_t)b * NKV + hkv) * HD * TT;

  auto stage = [&](int buf, int kt){
    #pragma unroll
    for (int ii = 0; ii < 4; ++ii){
      int c  = ii * 256 + tid;
      int ub = (ii * 256 + w * 64) * 8;
      int kr = c >> 4, kc = (c & 15) ^ (kr & 7);
      const u16* gk = kbase + (size_t)(kt * 64 + kr) * HD + kc * 8;
      __builtin_amdgcn_global_load_lds(AS1(gk), AS3(&Ks[buf][ub]), 16, 0, 0);
      int vr = c >> 3, vc = (c & 7) ^ (vr & 7);
      const u16* gv = vbase + (size_t)vr * TT + kt * 64 + vc * 8;
      __builtin_amdgcn_global_load_lds(AS1(gv), AS3(&Vs[buf][ub]), 16, 0, 0);
    }
  };

  int q0w = qt * 128 + w * 32;                  // wave's first q row (group A); B = +16

  bf16x8 aqA[4], aqB[4];
  #pragma unroll
  for (int s = 0; s < 4; ++s){
    aqA[s] = *(const bf16x8*)(qbase + (size_t)(q0w + j)      * HD + s*32 + lk);
    aqB[s] = *(const bf16x8*)(qbase + (size_t)(q0w + 16 + j) * HD + s*32 + lk);
  }

  f32x4 oA[8], oB[8];
  #pragma unroll
  for (int dt = 0; dt < 8; ++dt)
    #pragma unroll
    for (int r = 0; r < 4; ++r){ oA[dt][r] = 0.f; oB[dt][r] = 0.f; }
  float mA = -1e30f, lA = 0.f, mB = -1e30f, lB = 0.f;

  int nst = 2 * qt + 2;                         // kv tiles 0 .. 2qt+1
  stage(0, 0);
  int cur = 0;
  for (int kt = 0; kt < nst; ++kt){
    __builtin_amdgcn_s_barrier();               // all waves done reading buf cur^1
    if (kt + 1 < nst){
      stage(cur ^ 1, kt + 1);
      asm volatile("s_waitcnt vmcnt(8)" ::: "memory");   // stage(kt) landed
    } else {
      asm volatile("s_waitcnt vmcnt(0)" ::: "memory");
    }
    __builtin_amdgcn_s_barrier();               // buf cur fully populated

    // ---- scores (swapped): sc*[c] = K_c * Q -> D[row=kv][col=q], both q-groups share kf ----
    const u16* ks = Ks[cur];
    f32x4 scA[4], scB[4];
    #pragma unroll
    for (int c = 0; c < 4; ++c)
      #pragma unroll
      for (int r = 0; r < 4; ++r){ scA[c][r] = 0.f; scB[c][r] = 0.f; }
    __builtin_amdgcn_s_setprio(1);
    #pragma unroll
    for (int c = 0; c < 4; ++c){
      const u16* kp = ks + (c*16 + j) * 128;
      #pragma unroll
      for (int s = 0; s < 4; ++s){
        bf16x8 kf = *(const bf16x8*)(kp + (((s*32) + lk) ^ sw));
        scA[c] = __builtin_amdgcn_mfma_f32_16x16x32_bf16(kf, aqA[s], scA[c], 0, 0, 0);
        scB[c] = __builtin_amdgcn_mfma_f32_16x16x32_bf16(kf, aqB[s], scB[c], 0, 0, 0);
      }
    }
    __builtin_amdgcn_s_setprio(0);
    if (kt*64 + 63 > q0w){                      // wave-uniform: diagonal region
      int qgA = q0w + j, qgB = q0w + 16 + j;
      #pragma unroll
      for (int c = 0; c < 4; ++c)
        #pragma unroll
        for (int r = 0; r < 4; ++r){
          int kv = kt*64 + c*16 + g*4 + r;
          if (kv > qgA) scA[c][r] = -1e30f;
          if (kv > qgB) scB[c][r] = -1e30f;
        }
    }
    // ---- softmax group A ----
    {
      float tm = fmaxf(fmaxf(fmaxf(scA[0][0], scA[0][1]), fmaxf(scA[0][2], scA[0][3])),
                       fmaxf(fmaxf(scA[1][0], scA[1][1]), fmaxf(scA[1][2], scA[1][3])));
      tm = fmaxf(tm, fmaxf(fmaxf(fmaxf(scA[2][0], scA[2][1]), fmaxf(scA[2][2], scA[2][3])),
                           fmaxf(fmaxf(scA[3][0], scA[3][1]), fmaxf(scA[3][2], scA[3][3]))));
      tm = fmaxf(tm, __shfl_xor(tm, 16));
      tm = fmaxf(tm, __shfl_xor(tm, 32));
      if (__any((tm > mA + 8.f) ? 1 : 0)){
        float mnew  = fmaxf(mA, tm);
        float alpha = __expf(mA - mnew);
        mA = mnew; lA *= alpha;
        #pragma unroll
        for (int r = 0; r < 4; ++r){
          float ar = __shfl(alpha, (lane & 48) | (g*4 + r));
          #pragma unroll
          for (int dt = 0; dt < 8; ++dt) oA[dt][r] *= ar;
        }
      }
      float rs = 0.f;
      #pragma unroll
      for (int c = 0; c < 4; ++c)
        #pragma unroll
        for (int r = 0; r < 4; ++r){
          float p = __expf(scA[c][r] - mA);
          scA[c][r] = p; rs += p;
        }
      rs += __shfl_xor(rs, 16);
      rs += __shfl_xor(rs, 32);
      lA += rs;
    }
    // ---- softmax group B ----
    {
      float tm = fmaxf(fmaxf(fmaxf(scB[0][0], scB[0][1]), fmaxf(scB[0][2], scB[0][3])),
                       fmaxf(fmaxf(scB[1][0], scB[1][1]), fmaxf(scB[1][2], scB[1][3])));
      tm = fmaxf(tm, fmaxf(fmaxf(fmaxf(scB[2][0], scB[2][1]), fmaxf(scB[2][2], scB[2][3])),
                           fmaxf(fmaxf(scB[3][0], scB[3][1]), fmaxf(scB[3][2], scB[3][3]))));
      tm = fmaxf(tm, __shfl_xor(tm, 16));
      tm = fmaxf(tm, __shfl_xor(tm, 32));
      if (__any((tm > mB + 8.f) ? 1 : 0)){
        float mnew  = fmaxf(mB, tm);
        float alpha = __expf(mB - mnew);
        mB = mnew; lB *= alpha;
        #pragma unroll
        for (int r = 0; r < 4; ++r){
          float ar = __shfl(alpha, (lane & 48) | (g*4 + r));
          #pragma unroll
          for (int dt = 0; dt < 8; ++dt) oB[dt][r] *= ar;
        }
      }
      float rs = 0.f;
      #pragma unroll
      for (int c = 0; c < 4; ++c)
        #pragma unroll
        for (int r = 0; r < 4; ++r){
          float p = __expf(scB[c][r] - mB);
          scB[c][r] = p; rs += p;
        }
      rs += __shfl_xor(rs, 16);
      rs += __shfl_xor(rs, 32);
      lB += rs;
    }
    // ---- pack + register permutation -> PV A-fragments (r10-verified routes) ----
    u32 pkA[4][2], pkB[4][2];
    #pragma unroll
    for (int c = 0; c < 4; ++c){
      asm("v_cvt_pk_bf16_f32 %0, %1, %2" : "=v"(pkA[c][0]) : "v"(scA[c][0]), "v"(scA[c][1]));
      asm("v_cvt_pk_bf16_f32 %0, %1, %2" : "=v"(pkA[c][1]) : "v"(scA[c][2]), "v"(scA[c][3]));
      asm("v_cvt_pk_bf16_f32 %0, %1, %2" : "=v"(pkB[c][0]) : "v"(scB[c][0]), "v"(scB[c][1]));
      asm("v_cvt_pk_bf16_f32 %0, %1, %2" : "=v"(pkB[c][1]) : "v"(scB[c][2]), "v"(scB[c][3]));
    }
    bf16x8 paA[2], paB[2];
    #pragma unroll
    for (int kk = 0; kk < 2; ++kk){
      {
        u32 a0 = pkA[2*kk + gh][0],       a1 = pkA[2*kk + gh][1];
        u32 b0 = pkA[2*kk + (gh ^ 1)][0], b1 = pkA[2*kk + (gh ^ 1)][1];
        u32 v16_0 = (u32)__shfl_xor((int)a0, 16), v16_1 = (u32)__shfl_xor((int)a1, 16);
        u32 v32_0 = (u32)__shfl_xor((int)b0, 32), v32_1 = (u32)__shfl_xor((int)b1, 32);
        u32 v48_0 = (u32)__shfl_xor((int)b0, 48), v48_1 = (u32)__shfl_xor((int)b1, 48);
        union { u32 uw[4]; bf16x8 v; } u;
        u.uw[0] = (g==0) ? pkA[2*kk][0]   : (g==1) ? v48_0 : (g==2) ? v32_0 : v16_0;
        u.uw[1] = (g==0) ? pkA[2*kk][1]   : (g==1) ? v48_1 : (g==2) ? v32_1 : v16_1;
        u.uw[2] = (g==0) ? v16_0 : (g==1) ? v32_0 : (g==2) ? v48_0 : pkA[2*kk+1][0];
        u.uw[3] = (g==0) ? v16_1 : (g==1) ? v32_1 : (g==2) ? v48_1 : pkA[2*kk+1][1];
        paA[kk] = u.v;
      }
      {
        u32 a0 = pkB[2*kk + gh][0],       a1 = pkB[2*kk + gh][1];
        u32 b0 = pkB[2*kk + (gh ^ 1)][0], b1 = pkB[2*kk + (gh ^ 1)][1];
        u32 v16_0 = (u32)__shfl_xor((int)a0, 16), v16_1 = (u32)__shfl_xor((int)a1, 16);
        u32 v32_0 = (u32)__shfl_xor((int)b0, 32), v32_1 = (u32)__shfl_xor((int)b1, 32);
        u32 v48_0 = (u32)__shfl_xor((int)b0, 48), v48_1 = (u32)__shfl_xor((int)b1, 48);
        union { u32 uw[4]; bf16x8 v; } u;
        u.uw[0] = (g==0) ? pkB[2*kk][0]   : (g==1) ? v48_0 : (g==2) ? v32_0 : v16_0;
        u.uw[1] = (g==0) ? pkB[2*kk][1]   : (g==1) ? v48_1 : (g==2) ? v32_1 : v16_1;
        u.uw[2] = (g==0) ? v16_0 : (g==1) ? v32_0 : (g==2) ? v48_0 : pkB[2*kk+1][0];
        u.uw[3] = (g==0) ? v16_1 : (g==1) ? v32_1 : (g==2) ? v48_1 : pkB[2*kk+1][1];
        paB[kk] = u.v;
      }
    }
    // ---- O += P V, both groups share vf ----
    const u16* vs = Vs[cur];
    __builtin_amdgcn_s_setprio(1);
    #pragma unroll
    for (int dt = 0; dt < 8; ++dt){
      const u16* vp = vs + (dt*16 + j) * 64;
      #pragma unroll
      for (int kk = 0; kk < 2; ++kk){
        bf16x8 vf = *(const bf16x8*)(vp + (((kk*32) + lk) ^ sw));
        oA[dt] = __builtin_amdgcn_mfma_f32_16x16x32_bf16(paA[kk], vf, oA[dt], 0, 0, 0);
        oB[dt] = __builtin_amdgcn_mfma_f32_16x16x32_bf16(paB[kk], vf, oB[dt], 0, 0, 0);
      }
    }
    __builtin_amdgcn_s_setprio(0);
    cur ^= 1;
  }
  // ---- epilogue: both groups ----
  #pragma unroll
  for (int r = 0; r < 4; ++r){
    float lsA = __shfl(lA, (lane & 48) | (g*4 + r));
    float lsB = __shfl(lB, (lane & 48) | (g*4 + r));
    float invA = 1.0f / lsA, invB = 1.0f / lsB;
    int tA = q0w + g*4 + r, tB = tA + 16;
    size_t baseA = ((size_t)b * TT + tA) * EMBED + h * HD;
    size_t baseB = ((size_t)b * TT + tB) * EMBED + h * HD;
    #pragma unroll
    for (int dt = 0; dt < 8; ++dt){
      ob[baseA + dt*16 + j] = f2b(oA[dt][r] * invA);
      ob[baseB + dt*16 + j] = f2b(oB[dt][r] * invB);
    }
  }
}

extern "C" void kernel_launch(void* const* d_in, const int* in_sizes, int n_in,
                              void* d_out, int out_size, void* d_ws, size_t ws_size,
                              hipStream_t stream){
  const float* x  = (const float*)d_in[0];
  const float* Wq = (const float*)d_in[1];
  const float* Wk = (const float*)d_in[2];
  const float* Wv = (const float*)d_in[3];
  const float* Wo = (const float*)d_in[4];

  char* ws = (char*)d_ws;
  size_t off = 0;
  auto alloc = [&](size_t bytes){ void* p = ws + off; off += (bytes + 255) & ~(size_t)255; return p; };
  u16* xb    = (u16*)alloc((size_t)MROWS * EMBED * 2);
  u16* Wqkvt = (u16*)alloc((size_t)3072 * EMBED * 2);        // rows: 0..2047 Wq, 2048..2559 Wk, 2560..3071 Wv
  u16* Wot   = (u16*)alloc((size_t)EMBED * EMBED * 2);
  u16* qkv   = (u16*)alloc((QELEMS + 2*KELEMS) * 2);          // q | k | v contiguous
  u16* vtb   = (u16*)alloc(KELEMS * 2);
  u16* ob    = (u16*)alloc((size_t)MROWS * EMBED * 2);

  u16* qb = qkv;
  u16* kb = qb + QELEMS;
  u16* vb = kb + KELEMS;

  cvt_f32_bf16<<<(MROWS*EMBED/4 + 255)/256, 256, 0, stream>>>(x, xb, MROWS*EMBED/4);
  trans_w2<<<dim3(EMBED/32, EMBED/32, 2), 256, 0, stream>>>(Wq, Wqkvt, Wo, Wot, EMBED, EMBED);
  trans_w2<<<dim3(512/32,   EMBED/32, 2), 256, 0, stream>>>(Wk, Wqkvt + (size_t)2048*EMBED,
                                                            Wv, Wqkvt + (size_t)2560*EMBED, EMBED, 512);

  gemm_bt<2><<<(MROWS/128)*(3072/128), 256, 0, stream>>>(xb, Wqkvt, qkv, 3072, EMBED);
  trans_v<<<4*64*BB*NKV, 256, 0, stream>>>(vb, vtb);

  attn_kernel<<<BB*NH*16, 256, 0, stream>>>(qb, kb, vtb, ob);

  gemm_bt<0><<<(MROWS/128)*(EMBED/128), 256, 0, stream>>>(ob, Wot, d_out, EMBED, EMBED);
}